// Round 1
// baseline (3775.066 us; speedup 1.0000x reference)
//
#include <hip/hip_runtime.h>
#include <hip/hip_bf16.h>

// CGCNN: 3x CGConv + projection + mean-pool + 2-layer MLP.
// Decomposition: z@W = h[dst]@W_dst + h[src]@W_src + e@W_edge.
// Per hidden conv: node GEMM (100k x 128 -> 512 packed cols), fused edge
// kernel (gather + on-the-fly e@We + sigmoid*softplus + atomic scatter),
// residual ReLU. All fp32 this round (correctness baseline).

#define N_NODES 100000
#define N_EDGES 1600000
#define HID 128

// ---------------- conv1 (channels=3) ----------------
__global__ __launch_bounds__(256) void conv1_edge(
    const float* __restrict__ x, const int* __restrict__ ei,
    const float* __restrict__ ea,
    const float* __restrict__ Wf, const float* __restrict__ bf,
    const float* __restrict__ Ws, const float* __restrict__ bs,
    float* __restrict__ agg1) {
  int e = blockIdx.x * 256 + threadIdx.x;
  if (e >= N_EDGES) return;
  int src = ei[e], dst = ei[N_EDGES + e];
  float z[38];
#pragma unroll
  for (int k = 0; k < 3; ++k) z[k] = x[dst * 3 + k];
#pragma unroll
  for (int k = 0; k < 3; ++k) z[3 + k] = x[src * 3 + k];
  const float* er = ea + (long long)e * 32;
#pragma unroll
  for (int k = 0; k < 32; ++k) z[6 + k] = er[k];
#pragma unroll
  for (int c = 0; c < 3; ++c) {
    float f = bf[c], s = bs[c];
#pragma unroll
    for (int k = 0; k < 38; ++k) {
      f = fmaf(z[k], Wf[k * 3 + c], f);
      s = fmaf(z[k], Ws[k * 3 + c], s);
    }
    float sig = 1.f / (1.f + __expf(-f));
    float sp = fmaxf(s, 0.f) + log1pf(__expf(-fabsf(s)));
    atomicAdd(&agg1[dst * 3 + c], sig * sp);
  }
}

// ---------------- projection: h = relu((x+agg1) @ Wp + bp) ----------------
__global__ __launch_bounds__(256) void proj_kernel(
    const float* __restrict__ x, const float* __restrict__ agg1,
    const float* __restrict__ Wp, const float* __restrict__ bp,
    float* __restrict__ h) {
  long long i = (long long)blockIdx.x * 256 + threadIdx.x;
  if (i >= (long long)N_NODES * HID) return;
  int n = (int)(i >> 7), j = (int)(i & 127);
  float v0 = x[n * 3 + 0] + agg1[n * 3 + 0];
  float v1 = x[n * 3 + 1] + agg1[n * 3 + 1];
  float v2 = x[n * 3 + 2] + agg1[n * 3 + 2];
  float acc = bp[j];
  acc = fmaf(v0, Wp[0 * HID + j], acc);
  acc = fmaf(v1, Wp[1 * HID + j], acc);
  acc = fmaf(v2, Wp[2 * HID + j], acc);
  h[i] = fmaxf(acc, 0.f);
}

// ---------------- node transform GEMM ----------------
// P[n] layout (512): [ f_dst(128) | s_dst(128) | f_src(128) | s_src(128) ]
// jblk 0,1 -> Wf rows 0..127 ; 2,3 -> Ws rows 0..127 ;
// 4,5 -> Wf rows 128..255 ; 6,7 -> Ws rows 128..255
#define BM 64
#define BN 64
#define BK 32
__global__ __launch_bounds__(256) void node_gemm(
    const float* __restrict__ h, const float* __restrict__ Wf,
    const float* __restrict__ Ws, float* __restrict__ P) {
  __shared__ float As[BK][BM + 4];
  __shared__ float Bs[BK][BN + 4];
  int jblk = blockIdx.y;
  int sec = jblk >> 1;
  int colbase = (jblk & 1) * 64;
  const float* W = (sec == 0 || sec == 2) ? Wf : Ws;
  int rowoff = (sec >= 2) ? 128 : 0;
  int m0 = blockIdx.x * BM;
  int tid = threadIdx.x;
  int tx = tid & 15, ty = tid >> 4;
  float acc[4][4] = {};
  for (int k0 = 0; k0 < 128; k0 += BK) {
#pragma unroll
    for (int i = 0; i < 2; ++i) {
      int f = tid + i * 256;          // float4 id, 512 total
      int r = f >> 3, c4 = (f & 7) * 4;
      float4 v = {0.f, 0.f, 0.f, 0.f};
      int row = m0 + r;
      if (row < N_NODES)
        v = *(const float4*)&h[(long long)row * 128 + k0 + c4];
      As[c4 + 0][r] = v.x; As[c4 + 1][r] = v.y;
      As[c4 + 2][r] = v.z; As[c4 + 3][r] = v.w;
    }
#pragma unroll
    for (int i = 0; i < 2; ++i) {
      int f = tid + i * 256;
      int r = f >> 4, c4 = (f & 15) * 4;
      float4 v = *(const float4*)&W[(long long)(k0 + r + rowoff) * 128 + colbase + c4];
      *(float4*)&Bs[r][c4] = v;
    }
    __syncthreads();
#pragma unroll
    for (int k = 0; k < BK; ++k) {
      float4 a = *(const float4*)&As[k][ty * 4];
      float4 b = *(const float4*)&Bs[k][tx * 4];
      float av[4] = {a.x, a.y, a.z, a.w};
      float bv[4] = {b.x, b.y, b.z, b.w};
#pragma unroll
      for (int i = 0; i < 4; ++i)
#pragma unroll
        for (int j = 0; j < 4; ++j)
          acc[i][j] = fmaf(av[i], bv[j], acc[i][j]);
    }
    __syncthreads();
  }
#pragma unroll
  for (int i = 0; i < 4; ++i) {
    int row = m0 + ty * 4 + i;
    if (row < N_NODES) {
      float4 o = {acc[i][0], acc[i][1], acc[i][2], acc[i][3]};
      *(float4*)&P[(long long)row * 512 + jblk * 64 + tx * 4] = o;
    }
  }
}

// ---------------- fused edge message + scatter ----------------
// 128 threads per edge (2 waves); weight cols in VGPRs; edge_attr via
// wave-uniform scalar loads (readfirstlane).
__global__ __launch_bounds__(256) void edge_msg(
    const float* __restrict__ P, const int* __restrict__ ei,
    const float* __restrict__ ea,
    const float* __restrict__ Wf, const float* __restrict__ bf,
    const float* __restrict__ Ws, const float* __restrict__ bs,
    float* __restrict__ agg) {
  const int npairs = N_EDGES / 2;
  int c = threadIdx.x & 127;
  int half = threadIdx.x >> 7;
  float wf[32], ws[32];
#pragma unroll
  for (int k = 0; k < 32; ++k) {
    wf[k] = Wf[(256 + k) * HID + c];
    ws[k] = Ws[(256 + k) * HID + c];
  }
  float bfc = bf[c], bsc = bs[c];
  for (int p = blockIdx.x; p < npairs; p += gridDim.x) {
    int e = 2 * p + half;
    int e_u = __builtin_amdgcn_readfirstlane(e);
    int src = ei[e_u], dst = ei[N_EDGES + e_u];
    const float* er = ea + (long long)e_u * 32;
    float ef = bfc, es = bsc;
#pragma unroll
    for (int k = 0; k < 32; ++k) {
      float ev = er[k];
      ef = fmaf(ev, wf[k], ef);
      es = fmaf(ev, ws[k], es);
    }
    const float* Pd = P + (long long)dst * 512;
    const float* Psx = P + (long long)src * 512;
    ef += Pd[c] + Psx[256 + c];
    es += Pd[128 + c] + Psx[384 + c];
    float sig = 1.f / (1.f + __expf(-ef));
    float sp = fmaxf(es, 0.f) + log1pf(__expf(-fabsf(es)));
    atomicAdd(&agg[(long long)dst * HID + c], sig * sp);
  }
}

// ---------------- residual + relu (in place on h) ----------------
__global__ __launch_bounds__(256) void residual_relu(
    float* __restrict__ h, const float* __restrict__ agg) {
  long long i = ((long long)blockIdx.x * 256 + threadIdx.x) * 4;
  if (i >= (long long)N_NODES * HID) return;
  float4 hv = *(const float4*)&h[i];
  float4 av = *(const float4*)&agg[i];
  hv.x = fmaxf(hv.x + av.x, 0.f);
  hv.y = fmaxf(hv.y + av.y, 0.f);
  hv.z = fmaxf(hv.z + av.z, 0.f);
  hv.w = fmaxf(hv.w + av.w, 0.f);
  *(float4*)&h[i] = hv;
}

// ---------------- mean pool (atomic) ----------------
__global__ __launch_bounds__(256) void pool_kernel(
    const float* __restrict__ h, const int* __restrict__ batch,
    float* __restrict__ sums, float* __restrict__ cnts) {
  long long i = (long long)blockIdx.x * 256 + threadIdx.x;
  if (i >= (long long)N_NODES * HID) return;
  int n = (int)(i >> 7), c = (int)(i & 127);
  int b = batch[n];
  atomicAdd(&sums[b * HID + c], h[i]);
  if (c == 0) atomicAdd(&cnts[b], 1.f);
}

// ---------------- graph MLP ----------------
__global__ __launch_bounds__(128) void mlpA(
    const float* __restrict__ sums, const float* __restrict__ cnts,
    const float* __restrict__ W1, const float* __restrict__ b1,
    float* __restrict__ g) {
  __shared__ float pl[HID];
  int gr = blockIdx.x, j = threadIdx.x;
  float cnt = fmaxf(cnts[gr], 1.f);
  pl[j] = sums[gr * HID + j] / cnt;
  __syncthreads();
  float acc = b1[j];
#pragma unroll 8
  for (int k = 0; k < HID; ++k) acc = fmaf(pl[k], W1[k * HID + j], acc);
  g[gr * HID + j] = fmaxf(acc, 0.f);
}

__global__ __launch_bounds__(256) void mlpB(
    const float* __restrict__ g, const float* __restrict__ W2,
    const float* __restrict__ b2, float* __restrict__ out) {
  int t = threadIdx.x;
  if (t >= 64 * 3) return;
  int gr = t / 3, o = t % 3;
  float acc = b2[o];
#pragma unroll 8
  for (int k = 0; k < HID; ++k) acc = fmaf(g[gr * HID + k], W2[k * 3 + o], acc);
  out[t] = acc;
}

extern "C" void kernel_launch(void* const* d_in, const int* in_sizes, int n_in,
                              void* d_out, int out_size, void* d_ws, size_t ws_size,
                              hipStream_t stream) {
  const float* x   = (const float*)d_in[0];
  const int*   ei  = (const int*)d_in[1];
  const float* ea  = (const float*)d_in[2];
  const int*   bat = (const int*)d_in[3];
  const float* Wf1 = (const float*)d_in[4];
  const float* bf1 = (const float*)d_in[5];
  const float* Ws1 = (const float*)d_in[6];
  const float* bs1 = (const float*)d_in[7];
  const float* Wp  = (const float*)d_in[8];
  const float* bp  = (const float*)d_in[9];
  const float* Wf2 = (const float*)d_in[10];
  const float* bf2 = (const float*)d_in[11];
  const float* Ws2 = (const float*)d_in[12];
  const float* bs2 = (const float*)d_in[13];
  const float* Wf3 = (const float*)d_in[14];
  const float* bf3 = (const float*)d_in[15];
  const float* Ws3 = (const float*)d_in[16];
  const float* bs3 = (const float*)d_in[17];
  const float* W1  = (const float*)d_in[18];
  const float* b1  = (const float*)d_in[19];
  const float* W2  = (const float*)d_in[20];
  const float* b2  = (const float*)d_in[21];
  float* out = (float*)d_out;

  // workspace layout (256B aligned)
  char* w = (char*)d_ws;
  size_t off = 0;
  auto alloc = [&](size_t bytes) {
    void* p = w + off;
    off += (bytes + 255) & ~(size_t)255;
    return p;
  };
  float* agg1 = (float*)alloc((size_t)N_NODES * 3 * 4);        // 1.2 MB
  float* h    = (float*)alloc((size_t)N_NODES * HID * 4);      // 51.2 MB
  float* P    = (float*)alloc((size_t)N_NODES * 512 * 4);      // 204.8 MB
  float* agg  = (float*)alloc((size_t)N_NODES * HID * 4);      // 51.2 MB
  float* sums = (float*)alloc((size_t)64 * HID * 4);
  float* cnts = (float*)alloc((size_t)64 * 4);
  float* g    = (float*)alloc((size_t)64 * HID * 4);
  (void)ws_size;

  // ---- conv1 ----
  hipMemsetAsync(agg1, 0, (size_t)N_NODES * 3 * 4, stream);
  conv1_edge<<<(N_EDGES + 255) / 256, 256, 0, stream>>>(x, ei, ea, Wf1, bf1, Ws1, bs1, agg1);
  proj_kernel<<<(N_NODES * HID + 255) / 256, 256, 0, stream>>>(x, agg1, Wp, bp, h);

  dim3 ggrid((N_NODES + BM - 1) / BM, 8);
  const int EDGE_BLOCKS = 8192;
  const int RES_BLOCKS = (N_NODES * HID / 4 + 255) / 256;

  // ---- conv2 ----
  node_gemm<<<ggrid, 256, 0, stream>>>(h, Wf2, Ws2, P);
  hipMemsetAsync(agg, 0, (size_t)N_NODES * HID * 4, stream);
  edge_msg<<<EDGE_BLOCKS, 256, 0, stream>>>(P, ei, ea, Wf2, bf2, Ws2, bs2, agg);
  residual_relu<<<RES_BLOCKS, 256, 0, stream>>>(h, agg);

  // ---- conv3 ----
  node_gemm<<<ggrid, 256, 0, stream>>>(h, Wf3, Ws3, P);
  hipMemsetAsync(agg, 0, (size_t)N_NODES * HID * 4, stream);
  edge_msg<<<EDGE_BLOCKS, 256, 0, stream>>>(P, ei, ea, Wf3, bf3, Ws3, bs3, agg);
  residual_relu<<<RES_BLOCKS, 256, 0, stream>>>(h, agg);

  // ---- pool + MLP ----
  hipMemsetAsync(sums, 0, (size_t)(64 * HID + 64) * 4, stream);  // sums+cnts contiguous
  pool_kernel<<<(N_NODES * HID + 255) / 256, 256, 0, stream>>>(h, bat, sums, cnts);
  mlpA<<<64, 128, 0, stream>>>(sums, cnts, W1, b1, g);
  mlpB<<<1, 256, 0, stream>>>(g, W2, b2, out);
}